// Round 6
// baseline (117.186 us; speedup 1.0000x reference)
//
#include <hip/hip_runtime.h>
#include <math.h>

#define NN 512
#define FF 64
#define HH 4

// ---------------- ws layout (floats) ----------------
// dinv : [512]               off 0
// cvec : [512]               off 512
// T    : [B*H*N]   = 8192    off 1024
// q_t  : [B*H*N*F] = 2097152 off 9216
// kT   : [B*H*F*N] = 2097152 off 2106368

// S1: q+k projection in one block (512 thr, 4-row tiles, 512 blocks).
//     Side jobs while waves 4-7 stage x: wave0 -> dinv[blk], wave1 -> zero T
//     slice, wave2 -> zero cvec[blk].
__global__ __launch_bounds__(512) void k_s1(const float* __restrict__ x,
                                            const float* __restrict__ Wq,
                                            const float* __restrict__ bq,
                                            const float* __restrict__ Wk,
                                            const float* __restrict__ bk,
                                            const float* __restrict__ adj,
                                            float* __restrict__ q_t,
                                            float* __restrict__ kT,
                                            float* __restrict__ dinv,
                                            float* __restrict__ T,
                                            float* __restrict__ cvec) {
    __shared__ float x_lds[4][64];
    int blk = blockIdx.x, tid = threadIdx.x;
    int wave = tid >> 6, lane = tid & 63;
    int b = blk >> 7, itile = blk & 127;
    int i0 = itile * 4;

    if (wave >= 4) {
        int idx = tid - 256;
        x_lds[idx >> 6][idx & 63] = x[((long)b * NN + i0 + (idx >> 6)) * FF + (idx & 63)];
    } else if (wave == 0) {
        float acc = 0.f;
#pragma unroll
        for (int k = 0; k < 8; ++k) acc += adj[blk * NN + k * 64 + lane];
        for (int o = 32; o > 0; o >>= 1) acc += __shfl_xor(acc, o);
        if (lane == 0) dinv[blk] = 1.0f / sqrtf(acc + 1.0f);
    } else if (wave == 1) {
        if (lane < 16) T[blk * 16 + lane] = 0.f;
    } else if (wave == 2) {
        if (lane == 0) cvec[blk] = 0.f;
    }
    __syncthreads();

    int isK = tid >> 8, col = tid & 255;
    const float* W = isK ? Wk : Wq;
    float bv = (isK ? bk : bq)[col];
    float a0 = bv, a1 = bv, a2 = bv, a3 = bv;
#pragma unroll 8
    for (int cc = 0; cc < 64; ++cc) {
        float w = W[cc * 256 + col];
        a0 = fmaf(x_lds[0][cc], w, a0);
        a1 = fmaf(x_lds[1][cc], w, a1);
        a2 = fmaf(x_lds[2][cc], w, a2);
        a3 = fmaf(x_lds[3][cc], w, a3);
    }
    int h = col >> 6, f = col & 63;
    int bh = b * HH + h;
    if (!isK) {
        long base = ((long)bh * NN + i0) * FF + f;
        q_t[base] = a0; q_t[base + FF] = a1;
        q_t[base + 2 * FF] = a2; q_t[base + 3 * FF] = a3;
    } else {
        long base = ((long)bh * FF + f) * NN + i0;  // i0%4==0 -> 16B aligned
        *(float4*)(kT + base) = make_float4(a0, a1, a2, a3);
    }
}

// S2: scores -> softmax -> noradj weighting -> atomicAdd into T (+cvec).
//     512 threads (1 j each), 8 i-rows per block, 1024 blocks = 32 waves/CU.
__global__ __launch_bounds__(512) void k_s2(const float* __restrict__ q_t,
                                            const float* __restrict__ kT,
                                            const float* __restrict__ adj,
                                            const float* __restrict__ dinv,
                                            float* __restrict__ T,
                                            float* __restrict__ cvec) {
    __shared__ float q_lds[8][64];
    __shared__ float red[8][8];
    __shared__ float red2[8][8];
    int blk = blockIdx.x, tid = threadIdx.x;
    int itile = blk & 63, h = (blk >> 6) & 3, b = blk >> 8;
    int bh = b * HH + h, i0 = itile * 8;
    int wv = tid >> 6, lane = tid & 63;

    q_lds[tid >> 6][tid & 63] = q_t[((long)bh * NN + i0 + (tid >> 6)) * FF + (tid & 63)];
    __syncthreads();

    int j = tid;
    const float* kb = kT + (long)bh * FF * NN;
    float s[8];
#pragma unroll
    for (int r = 0; r < 8; ++r) s[r] = 0.f;
#pragma unroll 2
    for (int f4 = 0; f4 < 64; f4 += 4) {
        float kv[4];
#pragma unroll
        for (int u = 0; u < 4; ++u) kv[u] = kb[(f4 + u) * NN + j];
#pragma unroll
        for (int r = 0; r < 8; ++r) {
            float4 qv = *(const float4*)&q_lds[r][f4];
            s[r] = fmaf(qv.x, kv[0], s[r]);
            s[r] = fmaf(qv.y, kv[1], s[r]);
            s[r] = fmaf(qv.z, kv[2], s[r]);
            s[r] = fmaf(qv.w, kv[3], s[r]);
        }
    }
    const float scale = 0.125f;   // 1/sqrt(64)
#pragma unroll
    for (int r = 0; r < 8; ++r) {
        float v = s[r];
        for (int o = 32; o > 0; o >>= 1) v = fmaxf(v, __shfl_xor(v, o));
        if (lane == 0) red[r][wv] = v;
    }
    __syncthreads();
    float m[8];
#pragma unroll
    for (int r = 0; r < 8; ++r) {
        float v = red[r][0];
#pragma unroll
        for (int w = 1; w < 8; ++w) v = fmaxf(v, red[r][w]);
        m[r] = v;
    }
#pragma unroll
    for (int r = 0; r < 8; ++r) {
        s[r] = expf((s[r] - m[r]) * scale);
        float v = s[r];
        for (int o = 32; o > 0; o >>= 1) v += __shfl_xor(v, o);
        if (lane == 0) red2[r][wv] = v;
    }
    __syncthreads();
    float Zi[8];
#pragma unroll
    for (int r = 0; r < 8; ++r) {
        float v = red2[r][0];
#pragma unroll
        for (int w = 1; w < 8; ++w) v += red2[r][w];
        Zi[r] = 1.0f / v;
    }
    float dj = dinv[j];
    float pw = 0.f, cw = 0.f;
#pragma unroll
    for (int r = 0; r < 8; ++r) {
        int gi = i0 + r;
        float di = dinv[gi];
        float a = adj[(long)gi * NN + j] + (gi == j ? 1.f : 0.f);
        float t = di * a;
        pw = fmaf(t, s[r] * Zi[r], pw);
        cw += t;
    }
    atomicAdd(&T[bh * NN + j], pw * dj);
    if (b == 0 && h == 0) atomicAdd(&cvec[j], cw);
}

// S3: fused sxd + SpMM + FC + relu.
//     sxd[b,j,f] = x[b,j,f]*(blin[f]*dj^2*cvec[j] + sum_h (dj*T[bh,j])*Wlin[h,f])
//     out[b,i,:] = relu((dinv_i * sum_j A[i,j]*sxd[b,j,:]) @ Wfc + bfc)
//     1024 blocks, 2 rows each, 4-way j-split, LDS staging of j-scalars.
__global__ __launch_bounds__(256) void k_s3(const float* __restrict__ x,
                                            const float* __restrict__ T,
                                            const float* __restrict__ Wlin,
                                            const float* __restrict__ blin,
                                            const float* __restrict__ cvec,
                                            const float* __restrict__ adj,
                                            const float* __restrict__ dinv,
                                            const float* __restrict__ Wfc,
                                            const float* __restrict__ bfc,
                                            float* __restrict__ out) {
    __shared__ float4 u4_l[NN];      // dj*T[h][j], h=0..3
    __shared__ float  u0_l[NN];      // dj*dj*cvec[j]
    __shared__ float2 ad_l[NN];      // A[i0,j], A[i0+1,j] (identity folded)
    __shared__ float part[4][2][64];
    __shared__ float m_lds[2][64];
    __shared__ float part2[4][2][64];
    int blk = blockIdx.x, tid = threadIdx.x;
    int b = blk >> 8, itile = blk & 255;
    int i0 = itile * 2;

    for (int jj = tid; jj < NN; jj += 256) {
        float dj = dinv[jj];
        u0_l[jj] = dj * dj * cvec[jj];
        u4_l[jj] = make_float4(dj * T[(b * HH + 0) * NN + jj],
                               dj * T[(b * HH + 1) * NN + jj],
                               dj * T[(b * HH + 2) * NN + jj],
                               dj * T[(b * HH + 3) * NN + jj]);
        ad_l[jj] = make_float2(adj[(long)i0 * NN + jj] + (i0 == jj ? 1.f : 0.f),
                               adj[(long)(i0 + 1) * NN + jj] + (i0 + 1 == jj ? 1.f : 0.f));
    }
    __syncthreads();

    int f = tid & 63, jc = tid >> 6;
    int jb = jc * 128;
    float blf = blin[f];
    float4 wl = make_float4(Wlin[f], Wlin[64 + f], Wlin[128 + f], Wlin[192 + f]);
    const float* xb = x + (long)b * NN * FF + f;
    float a0 = 0.f, a1 = 0.f;
#pragma unroll 4
    for (int j = jb; j < jb + 128; ++j) {
        float xv = xb[(long)j * FF];
        float4 u = u4_l[j];
        float2 ad = ad_l[j];
        float S = blf * u0_l[j];
        S = fmaf(wl.x, u.x, S);
        S = fmaf(wl.y, u.y, S);
        S = fmaf(wl.z, u.z, S);
        S = fmaf(wl.w, u.w, S);
        float sx = xv * S;
        a0 = fmaf(ad.x, sx, a0);
        a1 = fmaf(ad.y, sx, a1);
    }
    part[jc][0][f] = a0;
    part[jc][1][f] = a1;
    __syncthreads();
    if (jc == 0) {
        m_lds[0][f] = (part[0][0][f] + part[1][0][f] + part[2][0][f] + part[3][0][f]) * dinv[i0];
        m_lds[1][f] = (part[0][1][f] + part[1][1][f] + part[2][1][f] + part[3][1][f]) * dinv[i0 + 1];
    }
    __syncthreads();
    float o0 = 0.f, o1 = 0.f;
    int c0 = jc * 16;
#pragma unroll
    for (int cc = 0; cc < 16; ++cc) {
        float w = Wfc[(c0 + cc) * FF + f];
        o0 = fmaf(m_lds[0][c0 + cc], w, o0);
        o1 = fmaf(m_lds[1][c0 + cc], w, o1);
    }
    part2[jc][0][f] = o0;
    part2[jc][1][f] = o1;
    __syncthreads();
    if (jc == 0) {
        float bb = bfc[f];
        float r0 = part2[0][0][f] + part2[1][0][f] + part2[2][0][f] + part2[3][0][f] + bb;
        float r1 = part2[0][1][f] + part2[1][1][f] + part2[2][1][f] + part2[3][1][f] + bb;
        out[((long)b * NN + i0) * FF + f]     = fmaxf(r0, 0.f);
        out[((long)b * NN + i0 + 1) * FF + f] = fmaxf(r1, 0.f);
    }
}

extern "C" void kernel_launch(void* const* d_in, const int* in_sizes, int n_in,
                              void* d_out, int out_size, void* d_ws, size_t ws_size,
                              hipStream_t stream) {
    const float* x    = (const float*)d_in[0];
    const float* adj  = (const float*)d_in[1];
    const float* Wq   = (const float*)d_in[2];
    const float* bq   = (const float*)d_in[3];
    const float* Wk   = (const float*)d_in[4];
    const float* bk   = (const float*)d_in[5];
    const float* Wlin = (const float*)d_in[6];
    const float* blin = (const float*)d_in[7];
    const float* Wfc  = (const float*)d_in[8];
    const float* bfc  = (const float*)d_in[9];
    float* out = (float*)d_out;

    float* ws   = (float*)d_ws;
    float* dinv = ws;                 // 512
    float* cvec = ws + 512;           // 512
    float* T    = ws + 1024;          // 8192
    float* q_t  = ws + 9216;          // 2097152
    float* kT   = ws + 2106368;       // 2097152

    k_s1<<<dim3(512), dim3(512), 0, stream>>>(x, Wq, bq, Wk, bk, adj, q_t, kT, dinv, T, cvec);
    k_s2<<<dim3(1024), dim3(512), 0, stream>>>(q_t, kT, adj, dinv, T, cvec);
    k_s3<<<dim3(1024), dim3(256), 0, stream>>>(x, T, Wlin, blin, cvec, adj, dinv, Wfc, bfc, out);
}